// Round 1
// baseline (853.972 us; speedup 1.0000x reference)
//
#include <hip/hip_runtime.h>
#include <hip/hip_bf16.h>

// MoE block: H=2048, F=8192, E=8, top-2, T=512 tokens. All inputs fp32.
// Sparse evaluation: router -> per-expert token lists -> fused gated GEMM1
// (W1,W3 -> h bf16) -> GEMM2 (W2 -> scaled atomic scatter into out).

#define HDIM 2048
#define FDIM 8192
#define NEXP 8
#define NTOK 512
#define MAXT 512

typedef __attribute__((ext_vector_type(8))) short short8;
typedef __attribute__((ext_vector_type(4))) float f32x4;

// fp32 -> bf16 round-to-nearest-even (upper 16 bits)
__device__ __forceinline__ unsigned f2bf1(float f) {
    unsigned u = __builtin_bit_cast(unsigned, f);
    return (u + 0x7FFFu + ((u >> 16) & 1u)) >> 16;
}
__device__ __forceinline__ unsigned packbf(float lo, float hi) {
    return f2bf1(lo) | (f2bf1(hi) << 16);
}

// LDS byte offsets with XOR swizzle (16B granularity) to break the
// stride-128B bank conflict on ds_read_b128 fragment reads (G4).
#define A_OFF(r, k) (((((r)*64) + (k)) * 2) ^ ((((r) & 7)) << 4))
#define B_OFF(n, k) (((((n)*64) + (k)) * 2) ^ ((((n) & 7)) << 4))

// ---------------------------------------------------------------- router
__global__ void moe_router(const float* __restrict__ x, const float* __restrict__ Wg,
                           int* __restrict__ counts, int* __restrict__ tok_id,
                           float* __restrict__ tok_w) {
    const int t = blockIdx.x;        // one token per block (1 wave)
    const int lane = threadIdx.x;    // 64 lanes
    const float* xr = x + (size_t)t * HDIM;
    float acc[8];
    #pragma unroll
    for (int e = 0; e < 8; ++e) acc[e] = 0.f;
    #pragma unroll 4
    for (int i = 0; i < HDIM / 64; ++i) {
        int h = lane + i * 64;
        float xv = xr[h];
        const float4* wr = (const float4*)(Wg + (size_t)h * 8);
        float4 wa = wr[0], wb = wr[1];
        acc[0] += xv * wa.x; acc[1] += xv * wa.y; acc[2] += xv * wa.z; acc[3] += xv * wa.w;
        acc[4] += xv * wb.x; acc[5] += xv * wb.y; acc[6] += xv * wb.z; acc[7] += xv * wb.w;
    }
    #pragma unroll
    for (int off = 32; off >= 1; off >>= 1) {
        #pragma unroll
        for (int e = 0; e < 8; ++e) acc[e] += __shfl_xor(acc[e], off);
    }
    if (lane == 0) {
        int e0 = 0;
        #pragma unroll
        for (int e = 1; e < 8; ++e) if (acc[e] > acc[e0]) e0 = e;
        int e1 = (e0 == 0) ? 1 : 0;
        #pragma unroll
        for (int e = 0; e < 8; ++e) if (e != e0 && acc[e] > acc[e1]) e1 = e;
        // renormalized top-2 softmax == pairwise softmax of the two logits
        float w0 = 1.f / (1.f + __expf(acc[e1] - acc[e0]));
        float w1 = 1.f - w0;
        int s0 = atomicAdd(&counts[e0], 1);
        tok_id[e0 * MAXT + s0] = t; tok_w[e0 * MAXT + s0] = w0;
        int s1 = atomicAdd(&counts[e1], 1);
        tok_id[e1 * MAXT + s1] = t; tok_w[e1 * MAXT + s1] = w1;
    }
}

__global__ void moe_scan(const int* __restrict__ counts, int* __restrict__ offsets) {
    if (threadIdx.x == 0) {
        int a = 0;
        for (int e = 0; e < NEXP; ++e) { offsets[e] = a; a += counts[e]; }
    }
}

// ---------------------------------------------------------------- GEMM1
// h[slot, n] = relu(x W1)[slot, n] * (x W3)[slot, n], bf16 out, compact rows.
// Tile: BM=128 tokens x BN=64 F-cols x BK=64. 256 thr, waves 2x2.
__global__ __launch_bounds__(256, 2)
void moe_gemm1(const float* __restrict__ x, const float* __restrict__ W1,
               const float* __restrict__ W3, const int* __restrict__ counts,
               const int* __restrict__ offsets, const int* __restrict__ tok_id,
               unsigned short* __restrict__ hbuf) {
    const int nt = blockIdx.x, mt = blockIdx.y, e = blockIdx.z;
    const int cnt = counts[e];
    if (mt * 128 >= cnt) return;
    const int n0 = nt * 64;
    const int tid = threadIdx.x;

    __shared__ __align__(16) unsigned char sA[128 * 64 * 2];
    __shared__ __align__(16) unsigned char sB1[64 * 64 * 2];
    __shared__ __align__(16) unsigned char sB3[64 * 64 * 2];

    // A staging: 2 threads/row, 32 consecutive fp32 each (gathered token rows)
    const int arow = tid >> 1;
    const int akb = (tid & 1) * 32;
    const int aslot = mt * 128 + arow;
    const int tok = tok_id[e * MAXT + (aslot < cnt ? aslot : cnt - 1)];
    const float* aptr = x + (size_t)tok * HDIM + akb;

    // B staging: thread covers k-pairs (bk,bk+1)+32j at 4 consecutive n.
    // bank = k/2 + (n&7)*4 -> conflict-free b32 pair-writes.
    const int bk = 2 * ((tid >> 2) & 15);
    const int bnb = 4 * ((tid & 3) + ((tid >> 6) & 3) * 4);
    const size_t wstride = (size_t)HDIM * FDIM;
    const float* b1p = W1 + (size_t)e * wstride + (size_t)bk * FDIM + n0 + bnb;
    const float* b3p = W3 + (size_t)e * wstride + (size_t)bk * FDIM + n0 + bnb;

    const int w = tid >> 6;
    const int l = tid & 63;
    const int wr = (w >> 1) * 64, wc = (w & 1) * 32;
    const int lr = l & 15, lk = (l >> 4) * 8;

    f32x4 acc1[4][2], acc3[4][2];
    #pragma unroll
    for (int mi = 0; mi < 4; ++mi)
        #pragma unroll
        for (int ni = 0; ni < 2; ++ni) { acc1[mi][ni] = (f32x4)0.f; acc3[mi][ni] = (f32x4)0.f; }

    for (int kt = 0; kt < HDIM / 64; ++kt) {
        // ---- stage A (fp32 -> bf16)
        const float4* ap = (const float4*)(aptr + kt * 64);
        float4 av[8];
        #pragma unroll
        for (int i = 0; i < 8; ++i) av[i] = ap[i];
        #pragma unroll
        for (int i = 0; i < 4; ++i) {
            uint4 q;
            q.x = packbf(av[2 * i].x, av[2 * i].y);
            q.y = packbf(av[2 * i].z, av[2 * i].w);
            q.z = packbf(av[2 * i + 1].x, av[2 * i + 1].y);
            q.w = packbf(av[2 * i + 1].z, av[2 * i + 1].w);
            *(uint4*)&sA[A_OFF(arow, akb + 8 * i)] = q;
        }
        // ---- stage B1/B3 (fp32 [K][N] -> bf16 [N][K] with k-pair packing)
        #pragma unroll
        for (int j = 0; j < 2; ++j) {
            const int kk = bk + 32 * j;
            const float* p1 = b1p + (size_t)(kt * 64 + 32 * j) * FDIM;
            float4 r0 = *(const float4*)p1;
            float4 r1 = *(const float4*)(p1 + FDIM);
            *(unsigned*)&sB1[B_OFF(bnb + 0, kk)] = packbf(r0.x, r1.x);
            *(unsigned*)&sB1[B_OFF(bnb + 1, kk)] = packbf(r0.y, r1.y);
            *(unsigned*)&sB1[B_OFF(bnb + 2, kk)] = packbf(r0.z, r1.z);
            *(unsigned*)&sB1[B_OFF(bnb + 3, kk)] = packbf(r0.w, r1.w);
            const float* p3 = b3p + (size_t)(kt * 64 + 32 * j) * FDIM;
            float4 s0 = *(const float4*)p3;
            float4 s1 = *(const float4*)(p3 + FDIM);
            *(unsigned*)&sB3[B_OFF(bnb + 0, kk)] = packbf(s0.x, s1.x);
            *(unsigned*)&sB3[B_OFF(bnb + 1, kk)] = packbf(s0.y, s1.y);
            *(unsigned*)&sB3[B_OFF(bnb + 2, kk)] = packbf(s0.z, s1.z);
            *(unsigned*)&sB3[B_OFF(bnb + 3, kk)] = packbf(s0.w, s1.w);
        }
        __syncthreads();
        // ---- compute
        #pragma unroll
        for (int ks = 0; ks < 2; ++ks) {
            const int kk = ks * 32 + lk;
            short8 a[4];
            #pragma unroll
            for (int mi = 0; mi < 4; ++mi)
                a[mi] = *(const short8*)&sA[A_OFF(wr + mi * 16 + lr, kk)];
            #pragma unroll
            for (int ni = 0; ni < 2; ++ni) {
                short8 b1 = *(const short8*)&sB1[B_OFF(wc + ni * 16 + lr, kk)];
                short8 b3 = *(const short8*)&sB3[B_OFF(wc + ni * 16 + lr, kk)];
                #pragma unroll
                for (int mi = 0; mi < 4; ++mi) {
                    acc1[mi][ni] = __builtin_amdgcn_mfma_f32_16x16x32_bf16(a[mi], b1, acc1[mi][ni], 0, 0, 0);
                    acc3[mi][ni] = __builtin_amdgcn_mfma_f32_16x16x32_bf16(a[mi], b3, acc3[mi][ni], 0, 0, 0);
                }
            }
        }
        __syncthreads();
    }
    // ---- epilogue: h = relu(h1)*h3 -> bf16 compact rows
    const int hbase = offsets[e] + mt * 128;
    #pragma unroll
    for (int mi = 0; mi < 4; ++mi)
        #pragma unroll
        for (int ni = 0; ni < 2; ++ni)
            #pragma unroll
            for (int r = 0; r < 4; ++r) {
                int rl = wr + mi * 16 + (l >> 4) * 4 + r;
                int sl = mt * 128 + rl;
                if (sl < cnt) {
                    float v1 = acc1[mi][ni][r];
                    v1 = v1 > 0.f ? v1 : 0.f;
                    float hv = v1 * acc3[mi][ni][r];
                    hbuf[(size_t)(hbase + rl) * FDIM + (n0 + wc + ni * 16 + lr)] =
                        (unsigned short)f2bf1(hv);
                }
            }
}

// ---------------------------------------------------------------- GEMM2
// out[t, n] += w * (h W2)[slot, n]. Tile 128x64x64, K=8192.
__global__ __launch_bounds__(256, 2)
void moe_gemm2(const unsigned short* __restrict__ hbuf, const float* __restrict__ W2,
               const int* __restrict__ counts, const int* __restrict__ offsets,
               const int* __restrict__ tok_id, const float* __restrict__ tok_w,
               float* __restrict__ out) {
    const int nt = blockIdx.x, mt = blockIdx.y, e = blockIdx.z;
    const int cnt = counts[e];
    if (mt * 128 >= cnt) return;
    const int n0 = nt * 64;
    const int tid = threadIdx.x;

    __shared__ __align__(16) unsigned char sA[128 * 64 * 2];
    __shared__ __align__(16) unsigned char sB[64 * 64 * 2];

    const int arow = tid >> 1;
    const int akb = (tid & 1) * 32;  // bf16 units
    const int hrow = offsets[e] + mt * 128 + arow;  // hbuf padded, no clamp needed
    const unsigned short* aptr = hbuf + (size_t)hrow * FDIM + akb;

    const int bk = 2 * ((tid >> 2) & 15);
    const int bnb = 4 * ((tid & 3) + ((tid >> 6) & 3) * 4);
    const float* b2p = W2 + (size_t)e * ((size_t)FDIM * HDIM) + (size_t)bk * HDIM + n0 + bnb;

    const int w = tid >> 6;
    const int l = tid & 63;
    const int wr = (w >> 1) * 64, wc = (w & 1) * 32;
    const int lr = l & 15, lk = (l >> 4) * 8;

    f32x4 acc[4][2];
    #pragma unroll
    for (int mi = 0; mi < 4; ++mi)
        #pragma unroll
        for (int ni = 0; ni < 2; ++ni) acc[mi][ni] = (f32x4)0.f;

    for (int kt = 0; kt < FDIM / 64; ++kt) {
        const uint4* ap = (const uint4*)(aptr + kt * 64);
        uint4 q0 = ap[0], q1 = ap[1], q2 = ap[2], q3 = ap[3];
        *(uint4*)&sA[A_OFF(arow, akb + 0)] = q0;
        *(uint4*)&sA[A_OFF(arow, akb + 8)] = q1;
        *(uint4*)&sA[A_OFF(arow, akb + 16)] = q2;
        *(uint4*)&sA[A_OFF(arow, akb + 24)] = q3;
        #pragma unroll
        for (int j = 0; j < 2; ++j) {
            const int kk = bk + 32 * j;
            const float* p = b2p + (size_t)(kt * 64 + 32 * j) * HDIM;
            float4 r0 = *(const float4*)p;
            float4 r1 = *(const float4*)(p + HDIM);
            *(unsigned*)&sB[B_OFF(bnb + 0, kk)] = packbf(r0.x, r1.x);
            *(unsigned*)&sB[B_OFF(bnb + 1, kk)] = packbf(r0.y, r1.y);
            *(unsigned*)&sB[B_OFF(bnb + 2, kk)] = packbf(r0.z, r1.z);
            *(unsigned*)&sB[B_OFF(bnb + 3, kk)] = packbf(r0.w, r1.w);
        }
        __syncthreads();
        #pragma unroll
        for (int ks = 0; ks < 2; ++ks) {
            const int kk = ks * 32 + lk;
            short8 a[4];
            #pragma unroll
            for (int mi = 0; mi < 4; ++mi)
                a[mi] = *(const short8*)&sA[A_OFF(wr + mi * 16 + lr, kk)];
            #pragma unroll
            for (int ni = 0; ni < 2; ++ni) {
                short8 b = *(const short8*)&sB[B_OFF(wc + ni * 16 + lr, kk)];
                #pragma unroll
                for (int mi = 0; mi < 4; ++mi)
                    acc[mi][ni] = __builtin_amdgcn_mfma_f32_16x16x32_bf16(a[mi], b, acc[mi][ni], 0, 0, 0);
            }
        }
        __syncthreads();
    }
    // ---- epilogue: scaled scatter-add (each out element touched by exactly 2 experts)
    #pragma unroll
    for (int mi = 0; mi < 4; ++mi)
        #pragma unroll
        for (int ni = 0; ni < 2; ++ni)
            #pragma unroll
            for (int r = 0; r < 4; ++r) {
                int rl = wr + mi * 16 + (l >> 4) * 4 + r;
                int sl = mt * 128 + rl;
                if (sl < cnt) {
                    int tk = tok_id[e * MAXT + sl];
                    float wgt = tok_w[e * MAXT + sl];
                    atomicAdd(&out[(size_t)tk * HDIM + (n0 + wc + ni * 16 + lr)],
                              wgt * acc[mi][ni][r]);
                }
            }
}

// ---------------------------------------------------------------- launch
extern "C" void kernel_launch(void* const* d_in, const int* in_sizes, int n_in,
                              void* d_out, int out_size, void* d_ws, size_t ws_size,
                              hipStream_t stream) {
    const float* x  = (const float*)d_in[0];
    const float* Wg = (const float*)d_in[1];
    const float* W1 = (const float*)d_in[2];
    const float* W2 = (const float*)d_in[3];
    const float* W3 = (const float*)d_in[4];
    float* out = (float*)d_out;

    char* ws = (char*)d_ws;
    int*   counts  = (int*)(ws + 0);       // 8 ints
    int*   offsets = (int*)(ws + 32);      // 8 ints
    int*   tok_id  = (int*)(ws + 64);      // 8*512 ints
    float* tok_w   = (float*)(ws + 64 + NEXP * MAXT * 4);
    unsigned short* hbuf = (unsigned short*)(ws + 65536);  // (1024+128) x 8192 bf16

    hipMemsetAsync(ws, 0, 64, stream);                                    // counts/offsets
    hipMemsetAsync(d_out, 0, (size_t)out_size * sizeof(float), stream);   // zero for atomics

    moe_router<<<NTOK, 64, 0, stream>>>(x, Wg, counts, tok_id, tok_w);
    moe_scan<<<1, 64, 0, stream>>>(counts, offsets);
    moe_gemm1<<<dim3(FDIM / 64, 4, NEXP), 256, 0, stream>>>(x, W1, W3, counts, offsets, tok_id, hbuf);
    moe_gemm2<<<dim3(HDIM / 64, 4, NEXP), 256, 0, stream>>>(hbuf, W2, counts, offsets, tok_id, tok_w, out);
}